// Round 9
// baseline (244.365 us; speedup 1.0000x reference)
//
#include <hip/hip_runtime.h>

typedef __attribute__((ext_vector_type(8))) short bf16x8;
typedef __attribute__((ext_vector_type(16))) float f32x16;
typedef __attribute__((ext_vector_type(8))) unsigned short ushort8;

#define N_BLADES 32
#define B_DIM 1024
#define IN_DIM 256
#define OUT_DIM 256
#define K_DIM (IN_DIM * N_BLADES)   // 8192
#define N_DIM (OUT_DIM * N_BLADES)  // 8192

// ---------- helpers ----------

__device__ __forceinline__ unsigned short f2bf(float f) {
    unsigned int u = __float_as_uint(f);
    u = (u + 0x7fff + ((u >> 16) & 1)) >> 16;   // RNE
    return (unsigned short)u;
}

__device__ __forceinline__ float gp_sign(int a, int b) {
    int swaps = 0;
#pragma unroll
    for (int i = 0; i < 5; ++i) {
        int mask = (~((1 << (i + 1)) - 1)) & 31;
        swaps += ((b >> i) & 1) * __popc(a & mask);
    }
    float s = (swaps & 1) ? -1.0f : 1.0f;
    if (a & b & 16) s = -s;
    return s;
}

__device__ __forceinline__ void gload_lds16(const void* g, void* l) {
    __builtin_amdgcn_global_load_lds(
        (const __attribute__((address_space(1))) unsigned int*)g,
        (__attribute__((address_space(3))) unsigned int*)l, 16, 0, 0);
}

#define FENCE() asm volatile("" ::: "memory")
#define BAR()    { FENCE(); __builtin_amdgcn_s_barrier(); FENCE(); }
#define SCHED0() __builtin_amdgcn_sched_barrier(0)
#define LGKM(n)  { asm volatile("s_waitcnt lgkmcnt(" #n ")" ::: "memory"); }
#define VMC(n)   { asm volatile("s_waitcnt vmcnt(" #n ")" ::: "memory"); }

// ---------- prep: cast fp32 -> bf16 (8 elems/thread) ----------
__global__ __launch_bounds__(256) void cast_kernel(const float4* __restrict__ x,
                                                   unsigned short* __restrict__ xb) {
    int t = blockIdx.x * 256 + threadIdx.x;
    float4 a = x[t * 2];
    float4 b = x[t * 2 + 1];
    ushort8 pk;
    pk[0] = f2bf(a.x); pk[1] = f2bf(a.y); pk[2] = f2bf(a.z); pk[3] = f2bf(a.w);
    pk[4] = f2bf(b.x); pk[5] = f2bf(b.y); pk[6] = f2bf(b.z); pk[7] = f2bf(b.w);
    *(ushort8*)(xb + (size_t)t * 8) = pk;
}

// ---------- uniform-j XOR shuffle + sign mask on a bf16 octet ----------
__device__ __forceinline__ bf16x8 shuffle_sign(bf16x8 v, int jx,
                                               unsigned int m0, unsigned int m1,
                                               unsigned int m2, unsigned int m3) {
    union { bf16x8 v8; unsigned int w[4]; } a, b;
    a.v8 = v;
    int s = jx >> 1;
    unsigned int t0 = (s & 1) ? a.w[1] : a.w[0];
    unsigned int t1 = (s & 1) ? a.w[0] : a.w[1];
    unsigned int t2 = (s & 1) ? a.w[3] : a.w[2];
    unsigned int t3 = (s & 1) ? a.w[2] : a.w[3];
    unsigned int u0 = (s & 2) ? t2 : t0;
    unsigned int u1 = (s & 2) ? t3 : t1;
    unsigned int u2 = (s & 2) ? t0 : t2;
    unsigned int u3 = (s & 2) ? t1 : t3;
    if (jx & 1) {
        u0 = (u0 >> 16) | (u0 << 16);
        u1 = (u1 >> 16) | (u1 << 16);
        u2 = (u2 >> 16) | (u2 << 16);
        u3 = (u3 >> 16) | (u3 << 16);
    }
    b.w[0] = u0 ^ m0; b.w[1] = u1 ^ m1; b.w[2] = u2 ^ m2; b.w[3] = u3 ^ m3;
    return b.v8;
}

// ================= GEMM, N ordered (k,o), 32x32x16 MFMA, subtile-major LDS =================
// Block = one k x 128 b-rows. BM=128 BN=256 BK=64, 8 waves (2Mx4N), wave 64x64.
// LDS: A ring2 x 16KB @0 + B ring4 x 32KB @32768 = 160KB (1 block/CU).
// LDS layout (both A and B): addr = panel(row>>5)*4096 + c16*512 + (row&31)*16
//   (c16 = 16B k-slot 0..7). A 32-row fragment read at fixed c16 is contiguous
//   512B -> conflict-free BY CONSTRUCTION (R8's XOR swizzle 4-way-conflicted:
//   32 rows over 8 slots). B staged via gload_lds with linear dest + re-decomposed
//   per-lane source; A reg-staged with matching ds_write map (rule #21).
// Deep-prefetch ledger identical to R8: entry pending {Ar(T+1) 2, Bg(T+2) 4};
//   VMC(10) -> Ar(T+1); VMC(6) -> Bg(T+2). Counted LGKM(8)/(2). 1 barrier/tile.

#define ROWB 16384    // bytes per K-row (8192 bf16)

__global__ __launch_bounds__(512, 1) void gemm_ko32_kernel(const unsigned short* __restrict__ xb,
                                                           const unsigned short* __restrict__ wb,
                                                           float* __restrict__ Cws) {
    __shared__ char lds[163840];   // A: 2x16KB @0; B: 4x32KB @32768

    const int tid  = threadIdx.x;
    const int lane = tid & 63;
    const int wid  = tid >> 6;          // 0..7
    const int wr   = wid >> 2;          // 0..1
    const int wc   = wid & 3;           // 0..3
    const int l31  = lane & 31;
    const int l5   = lane >> 5;

    const int  kblk = blockIdx.x;
    const long row0 = (long)blockIdx.y * 128;
    const int  jx   = kblk & 7;
    const int  kq   = (kblk >> 3) & 3;

    // ---- A reg-staging: thread t -> row rA = t&127, dest k-slots c0 and c0+4
    const int rA = tid & 127;
    const int c0 = tid >> 7;            // 0..3; both slots share m-octet q = c0
    const char* aSrcK = (const char*)xb + (row0 + rA) * ROWB;
    const int aoffB = ((c0 ^ kq) * 16);             // source byte of slot c0 (slot c0+4: +64)
    const int adst0 = (rA >> 5) * 4096 + c0 * 512 + (rA & 31) * 16;  // +2048 for c0+4

    unsigned int mk0, mk1, mk2, mk3;
    {
        unsigned int mw[4];
#pragma unroll
        for (int w_ = 0; w_ < 4; ++w_) {
            unsigned int m_ = 0;
#pragma unroll
            for (int e2 = 0; e2 < 2; ++e2) {
                int m = 8 * c0 + 2 * w_ + e2;
                if (gp_sign(m, m ^ kblk) < 0.0f) m_ |= 0x8000u << (16 * e2);
            }
            mw[w_] = m_;
        }
        mk0 = mw[0]; mk1 = mw[1]; mk2 = mw[2]; mk3 = mw[3];
    }

    // ---- B staging constants (linear LDS dest; source re-decomposed per lane)
    const int  tid16 = tid * 16;
    const char* bSrc = (const char*)wb + (long)((tid >> 8) * 32 + (tid & 31)) * ROWB
                       + ((tid >> 5) & 7) * 16;

    // ---- fragment-read lane bases (subtile-major)
    const int aL = (wr * 2) * 4096 + l5 * 512 + l31 * 16;
    const int bL = 32768 + (wc * 2) * 4096 + l5 * 512 + l31 * 16;

#define B_STAGE(br, kpb) { \
    _Pragma("unroll") for (int n = 0; n < 4; ++n) \
        gload_lds16(bSrc + (long)n * (64L * ROWB) + (kpb), \
                    lds + 32768 + (br) * 32768 + n * 8192 + tid16); }
#define A_LOAD_E(kpb) { \
    rAe0 = *(const bf16x8*)(aSrcK + (kpb) + aoffB); \
    rAe1 = *(const bf16x8*)(aSrcK + (kpb) + aoffB + 64); }
#define A_LOAD_O(kpb) { \
    rAo0 = *(const bf16x8*)(aSrcK + (kpb) + aoffB); \
    rAo1 = *(const bf16x8*)(aSrcK + (kpb) + aoffB + 64); }
#define A_WRITE_E(ab) { \
    bf16x8 s0_ = shuffle_sign(rAe0, jx, mk0, mk1, mk2, mk3); \
    bf16x8 s1_ = shuffle_sign(rAe1, jx, mk0, mk1, mk2, mk3); \
    *(bf16x8*)(lds + (ab) * 16384 + adst0) = s0_; \
    *(bf16x8*)(lds + (ab) * 16384 + adst0 + 2048) = s1_; }
#define A_WRITE_O(ab) { \
    bf16x8 s0_ = shuffle_sign(rAo0, jx, mk0, mk1, mk2, mk3); \
    bf16x8 s1_ = shuffle_sign(rAo1, jx, mk0, mk1, mk2, mk3); \
    *(bf16x8*)(lds + (ab) * 16384 + adst0) = s0_; \
    *(bf16x8*)(lds + (ab) * 16384 + adst0 + 2048) = s1_; }

// frag(mt, ks): A at ab*16384 + aL + mt*4096 + ks*1024; B at br*32768 + bL + nt*4096 + ks*1024
#define READ_G0(ab, br) { \
    aG0[0][0] = *(const bf16x8*)(lds + (ab)*16384 + aL + 0*4096 + 0*1024); \
    aG0[0][1] = *(const bf16x8*)(lds + (ab)*16384 + aL + 0*4096 + 1*1024); \
    aG0[1][0] = *(const bf16x8*)(lds + (ab)*16384 + aL + 1*4096 + 0*1024); \
    aG0[1][1] = *(const bf16x8*)(lds + (ab)*16384 + aL + 1*4096 + 1*1024); \
    bG0[0][0] = *(const bf16x8*)(lds + (br)*32768 + bL + 0*4096 + 0*1024); \
    bG0[0][1] = *(const bf16x8*)(lds + (br)*32768 + bL + 0*4096 + 1*1024); \
    bG0[1][0] = *(const bf16x8*)(lds + (br)*32768 + bL + 1*4096 + 0*1024); \
    bG0[1][1] = *(const bf16x8*)(lds + (br)*32768 + bL + 1*4096 + 1*1024); }
#define READ_G1(ab, br) { \
    aG1[0][0] = *(const bf16x8*)(lds + (ab)*16384 + aL + 0*4096 + 2*1024); \
    aG1[0][1] = *(const bf16x8*)(lds + (ab)*16384 + aL + 0*4096 + 3*1024); \
    aG1[1][0] = *(const bf16x8*)(lds + (ab)*16384 + aL + 1*4096 + 2*1024); \
    aG1[1][1] = *(const bf16x8*)(lds + (ab)*16384 + aL + 1*4096 + 3*1024); \
    bG1[0][0] = *(const bf16x8*)(lds + (br)*32768 + bL + 0*4096 + 2*1024); \
    bG1[0][1] = *(const bf16x8*)(lds + (br)*32768 + bL + 0*4096 + 3*1024); \
    bG1[1][0] = *(const bf16x8*)(lds + (br)*32768 + bL + 1*4096 + 2*1024); \
    bG1[1][1] = *(const bf16x8*)(lds + (br)*32768 + bL + 1*4096 + 3*1024); }
#define MFG0() \
    _Pragma("unroll") for (int s = 0; s < 2; ++s) \
    _Pragma("unroll") for (int mt = 0; mt < 2; ++mt) \
    _Pragma("unroll") for (int nt = 0; nt < 2; ++nt) \
        acc[mt][nt] = __builtin_amdgcn_mfma_f32_32x32x16_bf16(aG0[mt][s], bG0[nt][s], acc[mt][nt], 0, 0, 0);
#define MFG1() \
    _Pragma("unroll") for (int s = 0; s < 2; ++s) \
    _Pragma("unroll") for (int mt = 0; mt < 2; ++mt) \
    _Pragma("unroll") for (int nt = 0; nt < 2; ++nt) \
        acc[mt][nt] = __builtin_amdgcn_mfma_f32_32x32x16_bf16(aG1[mt][s], bG1[nt][s], acc[mt][nt], 0, 0, 0);

    f32x16 acc[2][2];
#pragma unroll
    for (int mt = 0; mt < 2; ++mt)
#pragma unroll
        for (int nt = 0; nt < 2; ++nt) acc[mt][nt] = (f32x16)0.0f;

    bf16x8 rAe0, rAe1, rAo0, rAo1;
    bf16x8 aG0[2][2], bG0[2][2], aG1[2][2], bG1[2][2];

    // ---- prologue (ledger-exact): end pending = {Ar(1) 2, Bg(2) 4}
    A_LOAD_E(0);            // Ar(0) [2]
    SCHED0();
    B_STAGE(0, 0);          // Bg(0) [6]
    B_STAGE(1, 128);        // Bg(1) [10]
    SCHED0();
    VMC(8);                 // Ar(0) done
    A_WRITE_E(0);           // A(0) -> abuf0
    SCHED0();
    A_LOAD_O(128);          // Ar(1) [pending Bg0,Bg1,Ar1 = 10]
    SCHED0();
    B_STAGE(2, 256);        // Bg(2) [14]
    SCHED0();
    VMC(6);                 // retire Bg0,Bg1 -> pending {Ar1, Bg2} = 6
    LGKM(0);                // A(0) writes done
    BAR();

    // body: T = tile index; ab=T&1, br=T&3; A loads ping-pong with T parity
#define TILE32(AB, ABN, BR, BRS, ALOAD, AWRITE, Texp) { \
    const int T_ = (Texp); \
    const int kAr = ((T_ + 2) & 127) << 7; \
    const int kBg = ((T_ + 3) & 127) << 7; \
    READ_G0(AB, BR); \
    SCHED0(); \
    READ_G1(AB, BR); \
    SCHED0(); \
    ALOAD(kAr);            /* Ar(T+2), 2 vm */ \
    SCHED0(); \
    B_STAGE(BRS, kBg);     /* Bg(T+3), 4 vm */ \
    SCHED0(); \
    LGKM(8); MFG0(); \
    VMC(10);               /* Ar(T+1) ready (issued tile T-1) */ \
    AWRITE(ABN); \
    SCHED0(); \
    LGKM(2); MFG1(); \
    LGKM(0); \
    VMC(6);                /* Bg(T+2) ready (issued tile T-1) */ \
    BAR(); }

    for (int t = 0; t < 32; ++t) {
        const int T4 = t * 4;
        TILE32(0, 1, 0, 3, A_LOAD_E, A_WRITE_O, T4);
        TILE32(1, 0, 1, 0, A_LOAD_O, A_WRITE_E, T4 + 1);
        TILE32(0, 1, 2, 1, A_LOAD_E, A_WRITE_O, T4 + 2);
        TILE32(1, 0, 3, 2, A_LOAD_O, A_WRITE_E, T4 + 3);
    }

    // ---- epilogue: 32x32 C/D layout col=lane&31, row=(r&3)+8*(r>>2)+4*l5 (m74/m101)
#pragma unroll
    for (int mt = 0; mt < 2; ++mt)
#pragma unroll
        for (int nt = 0; nt < 2; ++nt) {
            long c = (long)kblk * 256 + wc * 64 + nt * 32 + l31;
#pragma unroll
            for (int r = 0; r < 16; ++r) {
                int  rl = (r & 3) + 8 * (r >> 2) + 4 * l5;
                long rb = row0 + wr * 64 + mt * 32 + rl;
                Cws[rb * N_DIM + c] = acc[mt][nt][r];
            }
        }

#undef B_STAGE
#undef A_LOAD_E
#undef A_LOAD_O
#undef A_WRITE_E
#undef A_WRITE_O
#undef READ_G0
#undef READ_G1
#undef MFG0
#undef MFG1
#undef TILE32
}

// ---------- transpose: out[b][o*32+k] = Cws[b][k*256+o] ----------
__global__ __launch_bounds__(256) void transpose_kernel(const float* __restrict__ Cws,
                                                        float* __restrict__ out) {
    __shared__ float t[32 * 260];
    const int tid = threadIdx.x;
    const long b  = blockIdx.x;
    const float4* src = (const float4*)(Cws + b * N_DIM);
    float4*       dst = (float4*)(out + b * N_DIM);
#pragma unroll
    for (int r = 0; r < 8; ++r) {
        int f = tid + r * 256;
        float4 v = src[f];
        int k  = f >> 6;
        int c4 = (f & 63) * 4;
        *(float4*)&t[k * 260 + c4] = v;
    }
    __syncthreads();
#pragma unroll
    for (int r = 0; r < 8; ++r) {
        int g  = tid + r * 256;
        int o  = g >> 3;
        int k0 = (g & 7) * 4;
        float4 v;
        v.x = t[(k0 + 0) * 260 + o];
        v.y = t[(k0 + 1) * 260 + o];
        v.z = t[(k0 + 2) * 260 + o];
        v.w = t[(k0 + 3) * 260 + o];
        dst[g] = v;
    }
}

// ---------- fallback (ws tiny): direct fp32, correct but slow ----------
__global__ __launch_bounds__(256) void fallback_gp_kernel(const float* __restrict__ x,
                                                          const float* __restrict__ w,
                                                          float* __restrict__ out) {
    __shared__ float xs[IN_DIM * 32];
    __shared__ float tab[1024];
    int tid = threadIdx.x;
    for (int idx = tid; idx < 1024; idx += 256) {
        int m = idx >> 5, k = idx & 31;
        tab[idx] = gp_sign(m, m ^ k);
    }
    int b = blockIdx.x;
    const float4* xrow = (const float4*)(x + (long)b * K_DIM);
    float4* xs4 = (float4*)xs;
    for (int idx = tid; idx < 2048; idx += 256) xs4[idx] = xrow[idx];
    __syncthreads();

    int wid = tid >> 6, lane = tid & 63;
    int o = blockIdx.y * 8 + wid;
    int k = lane & 31, half = lane >> 5;
    float acc = 0.f;
    const float* wrow = w + (long)o * K_DIM + half * 4096;
    for (int i = 0; i < 128; ++i) {
        int ib = (half * 128 + i) * 32;
#pragma unroll
        for (int m = 0; m < 32; ++m) {
            acc += xs[ib + (m ^ k)] * tab[m * 32 + k] * wrow[i * 32 + m];
        }
    }
    acc += __shfl_down(acc, 32);
    if (half == 0) out[((long)b * OUT_DIM + o) * 32 + k] = acc;
}

// ---------- launch ----------
extern "C" void kernel_launch(void* const* d_in, const int* in_sizes, int n_in,
                              void* d_out, int out_size, void* d_ws, size_t ws_size,
                              hipStream_t stream) {
    const float* x = (const float*)d_in[0];
    const float* w = (const float*)d_in[1];
    float* out = (float*)d_out;

    const size_t xb_bytes  = (size_t)B_DIM * K_DIM * 2;          // 16 MiB
    const size_t wb_bytes  = (size_t)OUT_DIM * IN_DIM * 32 * 2;  // 4.2 MB
    const size_t cw_bytes  = (size_t)B_DIM * N_DIM * 4;          // 32 MiB
    const size_t need = xb_bytes + wb_bytes + cw_bytes;          // ~54 MB

    if (ws_size >= need) {
        unsigned short* xbp = (unsigned short*)d_ws;
        unsigned short* wbp = (unsigned short*)((char*)d_ws + xb_bytes);
        float*          cws = (float*)((char*)d_ws + xb_bytes + wb_bytes);

        cast_kernel<<<dim3(4096), dim3(256), 0, stream>>>((const float4*)x, xbp);
        cast_kernel<<<dim3(1024), dim3(256), 0, stream>>>((const float4*)w, wbp);
        gemm_ko32_kernel<<<dim3(32, 8), dim3(512), 0, stream>>>(xbp, wbp, cws);
        transpose_kernel<<<dim3(B_DIM), dim3(256), 0, stream>>>(cws, out);
    } else {
        fallback_gp_kernel<<<dim3(B_DIM, OUT_DIM / 8), dim3(256), 0, stream>>>(x, w, out);
    }
}

// Round 10
// 176.478 us; speedup vs baseline: 1.3847x; 1.3847x over previous
//
#include <hip/hip_runtime.h>

typedef __attribute__((ext_vector_type(8))) short bf16x8;
typedef __attribute__((ext_vector_type(16))) float f32x16;
typedef __attribute__((ext_vector_type(8))) unsigned short ushort8;

#define N_BLADES 32
#define B_DIM 1024
#define IN_DIM 256
#define OUT_DIM 256
#define K_DIM (IN_DIM * N_BLADES)   // 8192
#define N_DIM (OUT_DIM * N_BLADES)  // 8192

// ---------- helpers ----------

__device__ __forceinline__ unsigned short f2bf(float f) {
    unsigned int u = __float_as_uint(f);
    u = (u + 0x7fff + ((u >> 16) & 1)) >> 16;   // RNE
    return (unsigned short)u;
}

__device__ __forceinline__ float gp_sign(int a, int b) {
    int swaps = 0;
#pragma unroll
    for (int i = 0; i < 5; ++i) {
        int mask = (~((1 << (i + 1)) - 1)) & 31;
        swaps += ((b >> i) & 1) * __popc(a & mask);
    }
    float s = (swaps & 1) ? -1.0f : 1.0f;
    if (a & b & 16) s = -s;
    return s;
}

__device__ __forceinline__ void gload_lds16(const void* g, void* l) {
    __builtin_amdgcn_global_load_lds(
        (const __attribute__((address_space(1))) unsigned int*)g,
        (__attribute__((address_space(3))) unsigned int*)l, 16, 0, 0);
}

#define FENCE() asm volatile("" ::: "memory")
#define BAR()    { FENCE(); __builtin_amdgcn_s_barrier(); FENCE(); }
#define SCHED0() __builtin_amdgcn_sched_barrier(0)
#define LGKM(n)  { asm volatile("s_waitcnt lgkmcnt(" #n ")" ::: "memory"); }
#define VMC(n)   { asm volatile("s_waitcnt vmcnt(" #n ")" ::: "memory"); }

// ---------- prep: cast fp32 -> bf16 (8 elems/thread, row-major) ----------
__global__ __launch_bounds__(256) void cast_kernel(const float4* __restrict__ x,
                                                   unsigned short* __restrict__ xb) {
    int t = blockIdx.x * 256 + threadIdx.x;
    float4 a = x[t * 2];
    float4 b = x[t * 2 + 1];
    ushort8 pk;
    pk[0] = f2bf(a.x); pk[1] = f2bf(a.y); pk[2] = f2bf(a.z); pk[3] = f2bf(a.w);
    pk[4] = f2bf(b.x); pk[5] = f2bf(b.y); pk[6] = f2bf(b.z); pk[7] = f2bf(b.w);
    *(ushort8*)(xb + (size_t)t * 8) = pk;
}

// ---------- prep: cast + permute w into staged order ----------
// wb2 linear octet t = ((kt*8 + panel)*8 + c16)*32 + o31
//   value = w[o = panel*32+o31][k = kt*64 + c16*8 + e], bf16.
// => B_STAGE for tile kt reads CONTIGUOUS 32KB at wb2 + kt*32768.
__global__ __launch_bounds__(256) void cast_w_perm_kernel(const float* __restrict__ w,
                                                          unsigned short* __restrict__ wb2) {
    int t = blockIdx.x * 256 + threadIdx.x;    // 262144 octets
    int o31   = t & 31;
    int c16   = (t >> 5) & 7;
    int panel = (t >> 8) & 7;
    int kt    = t >> 11;
    int o  = panel * 32 + o31;
    int k0 = kt * 64 + c16 * 8;
    const float4* src = (const float4*)(w + (long)o * K_DIM + k0);
    float4 a = src[0], b = src[1];
    ushort8 pk;
    pk[0] = f2bf(a.x); pk[1] = f2bf(a.y); pk[2] = f2bf(a.z); pk[3] = f2bf(a.w);
    pk[4] = f2bf(b.x); pk[5] = f2bf(b.y); pk[6] = f2bf(b.z); pk[7] = f2bf(b.w);
    *(ushort8*)(wb2 + (size_t)t * 8) = pk;
}

// ---------- uniform-j XOR shuffle + sign mask on a bf16 octet ----------
__device__ __forceinline__ bf16x8 shuffle_sign(bf16x8 v, int jx,
                                               unsigned int m0, unsigned int m1,
                                               unsigned int m2, unsigned int m3) {
    union { bf16x8 v8; unsigned int w[4]; } a, b;
    a.v8 = v;
    int s = jx >> 1;
    unsigned int t0 = (s & 1) ? a.w[1] : a.w[0];
    unsigned int t1 = (s & 1) ? a.w[0] : a.w[1];
    unsigned int t2 = (s & 1) ? a.w[3] : a.w[2];
    unsigned int t3 = (s & 1) ? a.w[2] : a.w[3];
    unsigned int u0 = (s & 2) ? t2 : t0;
    unsigned int u1 = (s & 2) ? t3 : t1;
    unsigned int u2 = (s & 2) ? t0 : t2;
    unsigned int u3 = (s & 2) ? t1 : t3;
    if (jx & 1) {
        u0 = (u0 >> 16) | (u0 << 16);
        u1 = (u1 >> 16) | (u1 << 16);
        u2 = (u2 >> 16) | (u2 << 16);
        u3 = (u3 >> 16) | (u3 << 16);
    }
    b.w[0] = u0 ^ m0; b.w[1] = u1 ^ m1; b.w[2] = u2 ^ m2; b.w[3] = u3 ^ m3;
    return b.v8;
}

// ================= GEMM, N ordered (k,o), 32x32x16 MFMA, subtile-major LDS =================
// R9 structure (verified correct; conflicts=0) with COALESCED global sources:
//  - B staged from pre-permuted wb2: contiguous 8KB chunks, linear dest (identity perm).
//  - A: 4 threads/row (rA=tid>>2, c0=tid&3 -> slots c0,c0+4, one sign-mask set);
//    the 4 lanes' offsets (c0^kq)*16 permute {0,16,32,48} -> 64B contiguous per row.
// Ledger (per tile vm ops: Ar 2 + Bg 4): entry pending {Ar(T+1) 2, Bg(T+2) 4};
//   VMC(10) -> Ar(T+1); VMC(6) -> Bg(T+2). LGKM(8)/(2). 1 barrier/tile.

#define ROWB 16384    // bytes per K-row (8192 bf16)

__global__ __launch_bounds__(512, 1) void gemm_ko32_kernel(const unsigned short* __restrict__ xb,
                                                           const unsigned short* __restrict__ wb2,
                                                           float* __restrict__ Cws) {
    __shared__ char lds[163840];   // A: 2x16KB @0; B: 4x32KB @32768

    const int tid  = threadIdx.x;
    const int lane = tid & 63;
    const int wid  = tid >> 6;          // 0..7
    const int wr   = wid >> 2;          // 0..1
    const int wc   = wid & 3;           // 0..3
    const int l31  = lane & 31;
    const int l5   = lane >> 5;

    const int  kblk = blockIdx.x;
    const long row0 = (long)blockIdx.y * 128;
    const int  jx   = kblk & 7;
    const int  kq   = (kblk >> 3) & 3;

    // ---- A reg-staging: 4 threads/row; thread -> row rA=tid>>2, q=c0=tid&3, slots c0,c0+4
    const int rA = tid >> 2;
    const int c0 = tid & 3;
    const char* aSrcK = (const char*)xb + (row0 + rA) * ROWB;
    const int aoffB = (c0 ^ kq) * 16;               // source byte of slot c0 (slot c0+4: +64)
    const int adst0 = (rA >> 5) * 4096 + c0 * 512 + (rA & 31) * 16;  // +2048 for c0+4

    unsigned int mk0, mk1, mk2, mk3;
    {
        unsigned int mw[4];
#pragma unroll
        for (int w_ = 0; w_ < 4; ++w_) {
            unsigned int m_ = 0;
#pragma unroll
            for (int e2 = 0; e2 < 2; ++e2) {
                int m = 8 * c0 + 2 * w_ + e2;
                if (gp_sign(m, m ^ kblk) < 0.0f) m_ |= 0x8000u << (16 * e2);
            }
            mw[w_] = m_;
        }
        mk0 = mw[0]; mk1 = mw[1]; mk2 = mw[2]; mk3 = mw[3];
    }

    // ---- B staging: contiguous chunks from wb2 (identity perm both sides)
    const int  tid16 = tid * 16;
    const char* bSrc = (const char*)wb2 + tid16;

    // ---- fragment-read lane bases (subtile-major)
    const int aL = (wr * 2) * 4096 + l5 * 512 + l31 * 16;
    const int bL = 32768 + (wc * 2) * 4096 + l5 * 512 + l31 * 16;

#define B_STAGE(br, tb) { \
    _Pragma("unroll") for (int n = 0; n < 4; ++n) \
        gload_lds16(bSrc + (tb) + n * 8192, \
                    lds + 32768 + (br) * 32768 + n * 8192 + tid16); }
#define A_LOAD_E(kpb) { \
    rAe0 = *(const bf16x8*)(aSrcK + (kpb) + aoffB); \
    rAe1 = *(const bf16x8*)(aSrcK + (kpb) + aoffB + 64); }
#define A_LOAD_O(kpb) { \
    rAo0 = *(const bf16x8*)(aSrcK + (kpb) + aoffB); \
    rAo1 = *(const bf16x8*)(aSrcK + (kpb) + aoffB + 64); }
#define A_WRITE_E(ab) { \
    bf16x8 s0_ = shuffle_sign(rAe0, jx, mk0, mk1, mk2, mk3); \
    bf16x8 s1_ = shuffle_sign(rAe1, jx, mk0, mk1, mk2, mk3); \
    *(bf16x8*)(lds + (ab) * 16384 + adst0) = s0_; \
    *(bf16x8*)(lds + (ab) * 16384 + adst0 + 2048) = s1_; }
#define A_WRITE_O(ab) { \
    bf16x8 s0_ = shuffle_sign(rAo0, jx, mk0, mk1, mk2, mk3); \
    bf16x8 s1_ = shuffle_sign(rAo1, jx, mk0, mk1, mk2, mk3); \
    *(bf16x8*)(lds + (ab) * 16384 + adst0) = s0_; \
    *(bf16x8*)(lds + (ab) * 16384 + adst0 + 2048) = s1_; }

// frag(mt, ks): A at ab*16384 + aL + mt*4096 + ks*1024; B at br*32768 + bL + nt*4096 + ks*1024
#define READ_G0(ab, br) { \
    aG0[0][0] = *(const bf16x8*)(lds + (ab)*16384 + aL + 0*4096 + 0*1024); \
    aG0[0][1] = *(const bf16x8*)(lds + (ab)*16384 + aL + 0*4096 + 1*1024); \
    aG0[1][0] = *(const bf16x8*)(lds + (ab)*16384 + aL + 1*4096 + 0*1024); \
    aG0[1][1] = *(const bf16x8*)(lds + (ab)*16384 + aL + 1*4096 + 1*1024); \
    bG0[0][0] = *(const bf16x8*)(lds + (br)*32768 + bL + 0*4096 + 0*1024); \
    bG0[0][1] = *(const bf16x8*)(lds + (br)*32768 + bL + 0*4096 + 1*1024); \
    bG0[1][0] = *(const bf16x8*)(lds + (br)*32768 + bL + 1*4096 + 0*1024); \
    bG0[1][1] = *(const bf16x8*)(lds + (br)*32768 + bL + 1*4096 + 1*1024); }
#define READ_G1(ab, br) { \
    aG1[0][0] = *(const bf16x8*)(lds + (ab)*16384 + aL + 0*4096 + 2*1024); \
    aG1[0][1] = *(const bf16x8*)(lds + (ab)*16384 + aL + 0*4096 + 3*1024); \
    aG1[1][0] = *(const bf16x8*)(lds + (ab)*16384 + aL + 1*4096 + 2*1024); \
    aG1[1][1] = *(const bf16x8*)(lds + (ab)*16384 + aL + 1*4096 + 3*1024); \
    bG1[0][0] = *(const bf16x8*)(lds + (br)*32768 + bL + 0*4096 + 2*1024); \
    bG1[0][1] = *(const bf16x8*)(lds + (br)*32768 + bL + 0*4096 + 3*1024); \
    bG1[1][0] = *(const bf16x8*)(lds + (br)*32768 + bL + 1*4096 + 2*1024); \
    bG1[1][1] = *(const bf16x8*)(lds + (br)*32768 + bL + 1*4096 + 3*1024); }
#define MFG0() \
    _Pragma("unroll") for (int s = 0; s < 2; ++s) \
    _Pragma("unroll") for (int mt = 0; mt < 2; ++mt) \
    _Pragma("unroll") for (int nt = 0; nt < 2; ++nt) \
        acc[mt][nt] = __builtin_amdgcn_mfma_f32_32x32x16_bf16(aG0[mt][s], bG0[nt][s], acc[mt][nt], 0, 0, 0);
#define MFG1() \
    _Pragma("unroll") for (int s = 0; s < 2; ++s) \
    _Pragma("unroll") for (int mt = 0; mt < 2; ++mt) \
    _Pragma("unroll") for (int nt = 0; nt < 2; ++nt) \
        acc[mt][nt] = __builtin_amdgcn_mfma_f32_32x32x16_bf16(aG1[mt][s], bG1[nt][s], acc[mt][nt], 0, 0, 0);

    f32x16 acc[2][2];
#pragma unroll
    for (int mt = 0; mt < 2; ++mt)
#pragma unroll
        for (int nt = 0; nt < 2; ++nt) acc[mt][nt] = (f32x16)0.0f;

    bf16x8 rAe0, rAe1, rAo0, rAo1;
    bf16x8 aG0[2][2], bG0[2][2], aG1[2][2], bG1[2][2];

    // ---- prologue (ledger-exact): end pending = {Ar(1) 2, Bg(2) 4}
    A_LOAD_E(0);            // Ar(0) [2]
    SCHED0();
    B_STAGE(0, 0);          // Bg(0) [6]
    B_STAGE(1, 32768);      // Bg(1) [10]
    SCHED0();
    VMC(8);                 // Ar(0) done
    A_WRITE_E(0);           // A(0) -> abuf0
    SCHED0();
    A_LOAD_O(128);          // Ar(1) [pending Bg0,Bg1,Ar1 = 10]
    SCHED0();
    B_STAGE(2, 65536);      // Bg(2) [14]
    SCHED0();
    VMC(6);                 // retire Bg0,Bg1 -> pending {Ar1, Bg2} = 6
    LGKM(0);                // A(0) writes done
    BAR();

    // body: T = tile index; ab=T&1, br=T&3; A loads ping-pong with T parity
#define TILE32(AB, ABN, BR, BRS, ALOAD, AWRITE, Texp) { \
    const int T_ = (Texp); \
    const int  kAr = ((T_ + 2) & 127) << 7; \
    const long kBg = (long)((T_ + 3) & 127) << 15; \
    READ_G0(AB, BR); \
    SCHED0(); \
    READ_G1(AB, BR); \
    SCHED0(); \
    ALOAD(kAr);            /* Ar(T+2), 2 vm */ \
    SCHED0(); \
    B_STAGE(BRS, kBg);     /* Bg(T+3), 4 vm */ \
    SCHED0(); \
    LGKM(8); MFG0(); \
    VMC(10);               /* Ar(T+1) ready (issued tile T-1) */ \
    AWRITE(ABN); \
    SCHED0(); \
    LGKM(2); MFG1(); \
    LGKM(0); \
    VMC(6);                /* Bg(T+2) ready (issued tile T-1) */ \
    BAR(); }

    for (int t = 0; t < 32; ++t) {
        const int T4 = t * 4;
        TILE32(0, 1, 0, 3, A_LOAD_E, A_WRITE_O, T4);
        TILE32(1, 0, 1, 0, A_LOAD_O, A_WRITE_E, T4 + 1);
        TILE32(0, 1, 2, 1, A_LOAD_E, A_WRITE_O, T4 + 2);
        TILE32(1, 0, 3, 2, A_LOAD_O, A_WRITE_E, T4 + 3);
    }

    // ---- epilogue: 32x32 C/D layout col=lane&31, row=(r&3)+8*(r>>2)+4*l5 (m74/m101)
#pragma unroll
    for (int mt = 0; mt < 2; ++mt)
#pragma unroll
        for (int nt = 0; nt < 2; ++nt) {
            long c = (long)kblk * 256 + wc * 64 + nt * 32 + l31;
#pragma unroll
            for (int r = 0; r < 16; ++r) {
                int  rl = (r & 3) + 8 * (r >> 2) + 4 * l5;
                long rb = row0 + wr * 64 + mt * 32 + rl;
                Cws[rb * N_DIM + c] = acc[mt][nt][r];
            }
        }

#undef B_STAGE
#undef A_LOAD_E
#undef A_LOAD_O
#undef A_WRITE_E
#undef A_WRITE_O
#undef READ_G0
#undef READ_G1
#undef MFG0
#undef MFG1
#undef TILE32
}

// ---------- transpose: out[b][o*32+k] = Cws[b][k*256+o] ----------
__global__ __launch_bounds__(256) void transpose_kernel(const float* __restrict__ Cws,
                                                        float* __restrict__ out) {
    __shared__ float t[32 * 260];
    const int tid = threadIdx.x;
    const long b  = blockIdx.x;
    const float4* src = (const float4*)(Cws + b * N_DIM);
    float4*       dst = (float4*)(out + b * N_DIM);
#pragma unroll
    for (int r = 0; r < 8; ++r) {
        int f = tid + r * 256;
        float4 v = src[f];
        int k  = f >> 6;
        int c4 = (f & 63) * 4;
        *(float4*)&t[k * 260 + c4] = v;
    }
    __syncthreads();
#pragma unroll
    for (int r = 0; r < 8; ++r) {
        int g  = tid + r * 256;
        int o  = g >> 3;
        int k0 = (g & 7) * 4;
        float4 v;
        v.x = t[(k0 + 0) * 260 + o];
        v.y = t[(k0 + 1) * 260 + o];
        v.z = t[(k0 + 2) * 260 + o];
        v.w = t[(k0 + 3) * 260 + o];
        dst[g] = v;
    }
}

// ---------- fallback (ws tiny): direct fp32, correct but slow ----------
__global__ __launch_bounds__(256) void fallback_gp_kernel(const float* __restrict__ x,
                                                          const float* __restrict__ w,
                                                          float* __restrict__ out) {
    __shared__ float xs[IN_DIM * 32];
    __shared__ float tab[1024];
    int tid = threadIdx.x;
    for (int idx = tid; idx < 1024; idx += 256) {
        int m = idx >> 5, k = idx & 31;
        tab[idx] = gp_sign(m, m ^ k);
    }
    int b = blockIdx.x;
    const float4* xrow = (const float4*)(x + (long)b * K_DIM);
    float4* xs4 = (float4*)xs;
    for (int idx = tid; idx < 2048; idx += 256) xs4[idx] = xrow[idx];
    __syncthreads();

    int wid = tid >> 6, lane = tid & 63;
    int o = blockIdx.y * 8 + wid;
    int k = lane & 31, half = lane >> 5;
    float acc = 0.f;
    const float* wrow = w + (long)o * K_DIM + half * 4096;
    for (int i = 0; i < 128; ++i) {
        int ib = (half * 128 + i) * 32;
#pragma unroll
        for (int m = 0; m < 32; ++m) {
            acc += xs[ib + (m ^ k)] * tab[m * 32 + k] * wrow[i * 32 + m];
        }
    }
    acc += __shfl_down(acc, 32);
    if (half == 0) out[((long)b * OUT_DIM + o) * 32 + k] = acc;
}

// ---------- launch ----------
extern "C" void kernel_launch(void* const* d_in, const int* in_sizes, int n_in,
                              void* d_out, int out_size, void* d_ws, size_t ws_size,
                              hipStream_t stream) {
    const float* x = (const float*)d_in[0];
    const float* w = (const float*)d_in[1];
    float* out = (float*)d_out;

    const size_t xb_bytes  = (size_t)B_DIM * K_DIM * 2;          // 16 MiB
    const size_t wb_bytes  = (size_t)OUT_DIM * IN_DIM * 32 * 2;  // 4.2 MB
    const size_t cw_bytes  = (size_t)B_DIM * N_DIM * 4;          // 32 MiB
    const size_t need = xb_bytes + wb_bytes + cw_bytes;          // ~54 MB

    if (ws_size >= need) {
        unsigned short* xbp = (unsigned short*)d_ws;
        unsigned short* wbp = (unsigned short*)((char*)d_ws + xb_bytes);
        float*          cws = (float*)((char*)d_ws + xb_bytes + wb_bytes);

        cast_kernel<<<dim3(4096), dim3(256), 0, stream>>>((const float4*)x, xbp);
        cast_w_perm_kernel<<<dim3(1024), dim3(256), 0, stream>>>(w, wbp);
        gemm_ko32_kernel<<<dim3(32, 8), dim3(512), 0, stream>>>(xbp, wbp, cws);
        transpose_kernel<<<dim3(B_DIM), dim3(256), 0, stream>>>(cws, out);
    } else {
        fallback_gp_kernel<<<dim3(B_DIM, OUT_DIM / 8), dim3(256), 0, stream>>>(x, w, out);
    }
}

// Round 11
// 162.211 us; speedup vs baseline: 1.5065x; 1.0880x over previous
//
#include <hip/hip_runtime.h>

typedef __attribute__((ext_vector_type(8))) short bf16x8;
typedef __attribute__((ext_vector_type(16))) float f32x16;
typedef __attribute__((ext_vector_type(8))) unsigned short ushort8;

#define N_BLADES 32
#define B_DIM 1024
#define IN_DIM 256
#define OUT_DIM 256
#define K_DIM (IN_DIM * N_BLADES)   // 8192
#define N_DIM (OUT_DIM * N_BLADES)  // 8192

// ---------- helpers ----------

__device__ __forceinline__ unsigned short f2bf(float f) {
    unsigned int u = __float_as_uint(f);
    u = (u + 0x7fff + ((u >> 16) & 1)) >> 16;   // RNE
    return (unsigned short)u;
}

__device__ __forceinline__ float gp_sign(int a, int b) {
    int swaps = 0;
#pragma unroll
    for (int i = 0; i < 5; ++i) {
        int mask = (~((1 << (i + 1)) - 1)) & 31;
        swaps += ((b >> i) & 1) * __popc(a & mask);
    }
    float s = (swaps & 1) ? -1.0f : 1.0f;
    if (a & b & 16) s = -s;
    return s;
}

__device__ __forceinline__ void gload_lds16(const void* g, void* l) {
    __builtin_amdgcn_global_load_lds(
        (const __attribute__((address_space(1))) unsigned int*)g,
        (__attribute__((address_space(3))) unsigned int*)l, 16, 0, 0);
}

#define FENCE() asm volatile("" ::: "memory")
#define BAR()    { FENCE(); __builtin_amdgcn_s_barrier(); FENCE(); }
#define SCHED0() __builtin_amdgcn_sched_barrier(0)
#define LGKM(n)  { asm volatile("s_waitcnt lgkmcnt(" #n ")" ::: "memory"); }
#define VMC(n)   { asm volatile("s_waitcnt vmcnt(" #n ")" ::: "memory"); }

// ---------- prep: cast fp32 -> bf16 (8 elems/thread, row-major) ----------
__global__ __launch_bounds__(256) void cast_kernel(const float4* __restrict__ x,
                                                   unsigned short* __restrict__ xb) {
    int t = blockIdx.x * 256 + threadIdx.x;
    float4 a = x[t * 2];
    float4 b = x[t * 2 + 1];
    ushort8 pk;
    pk[0] = f2bf(a.x); pk[1] = f2bf(a.y); pk[2] = f2bf(a.z); pk[3] = f2bf(a.w);
    pk[4] = f2bf(b.x); pk[5] = f2bf(b.y); pk[6] = f2bf(b.z); pk[7] = f2bf(b.w);
    *(ushort8*)(xb + (size_t)t * 8) = pk;
}

// ---------- prep: cast + permute w into staged order ----------
// wb2 linear octet t = ((kt*8 + panel)*8 + c16)*32 + o31
//   value = w[o = panel*32+o31][k = kt*64 + c16*8 + e], bf16.
// => B_STAGE for tile kt reads CONTIGUOUS 32KB at wb2 + kt*32768.
__global__ __launch_bounds__(256) void cast_w_perm_kernel(const float* __restrict__ w,
                                                          unsigned short* __restrict__ wb2) {
    int t = blockIdx.x * 256 + threadIdx.x;    // 262144 octets
    int o31   = t & 31;
    int c16   = (t >> 5) & 7;
    int panel = (t >> 8) & 7;
    int kt    = t >> 11;
    int o  = panel * 32 + o31;
    int k0 = kt * 64 + c16 * 8;
    const float4* src = (const float4*)(w + (long)o * K_DIM + k0);
    float4 a = src[0], b = src[1];
    ushort8 pk;
    pk[0] = f2bf(a.x); pk[1] = f2bf(a.y); pk[2] = f2bf(a.z); pk[3] = f2bf(a.w);
    pk[4] = f2bf(b.x); pk[5] = f2bf(b.y); pk[6] = f2bf(b.z); pk[7] = f2bf(b.w);
    *(ushort8*)(wb2 + (size_t)t * 8) = pk;
}

// ---------- uniform-j XOR shuffle + sign mask on a bf16 octet ----------
__device__ __forceinline__ bf16x8 shuffle_sign(bf16x8 v, int jx,
                                               unsigned int m0, unsigned int m1,
                                               unsigned int m2, unsigned int m3) {
    union { bf16x8 v8; unsigned int w[4]; } a, b;
    a.v8 = v;
    int s = jx >> 1;
    unsigned int t0 = (s & 1) ? a.w[1] : a.w[0];
    unsigned int t1 = (s & 1) ? a.w[0] : a.w[1];
    unsigned int t2 = (s & 1) ? a.w[3] : a.w[2];
    unsigned int t3 = (s & 1) ? a.w[2] : a.w[3];
    unsigned int u0 = (s & 2) ? t2 : t0;
    unsigned int u1 = (s & 2) ? t3 : t1;
    unsigned int u2 = (s & 2) ? t0 : t2;
    unsigned int u3 = (s & 2) ? t1 : t3;
    if (jx & 1) {
        u0 = (u0 >> 16) | (u0 << 16);
        u1 = (u1 >> 16) | (u1 << 16);
        u2 = (u2 >> 16) | (u2 << 16);
        u3 = (u3 >> 16) | (u3 << 16);
    }
    b.w[0] = u0 ^ m0; b.w[1] = u1 ^ m1; b.w[2] = u2 ^ m2; b.w[3] = u3 ^ m3;
    return b.v8;
}

// ================= GEMM, N ordered (k,o), 32x32x16 MFMA, subtile-major LDS =================
// R10 structure with two fixes:
//  (1) A-layout bank swizzle: pos' = (row&31) ^ ((slot&3)<<1). Each in-order group
//      of 8 writing lanes (rA=2g,2g+1 x c0=0..3) now covers pos' = r0^{0..7} ->
//      distinct banks -> ds_write conflict-free (R10: 4-way, 1.27e7 conflicts).
//      Reads stay permuted-contiguous 512B chunks -> conflict-free. B unswizzled.
//  (2) Single entry-wait tile body: VMC(4) at tile start retires Bg(T+1)+Ar(T+1)
//      (issued >=1 tile earlier); AWRITE first; LGKM(8)->MFG0, LGKM(0)->MFG1;
//      no mid-MFMA vmcnt, no end-of-tile drain (ring-4 B defers Bg retirement).
// Ledger invariant at tile entry: pending = {Bg(T+1) 4, Ar(T+1) 2, Bg(T+2) 4} = 10.

#define ROWB 16384    // bytes per K-row (8192 bf16)

__global__ __launch_bounds__(512, 1) void gemm_ko32_kernel(const unsigned short* __restrict__ xb,
                                                           const unsigned short* __restrict__ wb2,
                                                           float* __restrict__ Cws) {
    __shared__ char lds[163840];   // A: 2x16KB @0; B: 4x32KB @32768

    const int tid  = threadIdx.x;
    const int lane = tid & 63;
    const int wid  = tid >> 6;          // 0..7
    const int wr   = wid >> 2;          // 0..1
    const int wc   = wid & 3;           // 0..3
    const int l31  = lane & 31;
    const int l5   = lane >> 5;

    const int  kblk = blockIdx.x;
    const long row0 = (long)blockIdx.y * 128;
    const int  jx   = kblk & 7;
    const int  kq   = (kblk >> 3) & 3;

    // ---- A reg-staging: 4 threads/row; thread -> row rA=tid>>2, q=c0=tid&3, slots c0,c0+4
    const int rA = tid >> 2;
    const int c0 = tid & 3;
    const char* aSrcK = (const char*)xb + (row0 + rA) * ROWB;
    const int aoffB = (c0 ^ kq) * 16;               // source byte of slot c0 (slot c0+4: +64)
    // swizzled dest: pos' = (rA&31) ^ (c0<<1)   (slot c0 and c0+4 share slot&3 = c0)
    const int adst0 = (rA >> 5) * 4096 + c0 * 512 + (((rA & 31) ^ (c0 << 1)) * 16);  // +2048 for c0+4

    unsigned int mk0, mk1, mk2, mk3;
    {
        unsigned int mw[4];
#pragma unroll
        for (int w_ = 0; w_ < 4; ++w_) {
            unsigned int m_ = 0;
#pragma unroll
            for (int e2 = 0; e2 < 2; ++e2) {
                int m = 8 * c0 + 2 * w_ + e2;
                if (gp_sign(m, m ^ kblk) < 0.0f) m_ |= 0x8000u << (16 * e2);
            }
            mw[w_] = m_;
        }
        mk0 = mw[0]; mk1 = mw[1]; mk2 = mw[2]; mk3 = mw[3];
    }

    // ---- B staging: contiguous chunks from wb2 (identity perm both sides)
    const int  tid16 = tid * 16;
    const char* bSrc = (const char*)wb2 + tid16;

    // ---- fragment-read bases: panel base + per-ks column offsets
    const int aLp = wr * 8192;              // A panel base (mt adds 4096)
    const int bLp = 32768 + wc * 8192;      // B panel base (nt adds 4096)
    // A cols carry the (slot&3)<<1 swizzle; B cols are plain
    const int aC0 = (0 + l5) * 512 + ((l31 ^ (((0 + l5) & 3) << 1)) * 16);
    const int aC1 = (2 + l5) * 512 + ((l31 ^ (((2 + l5) & 3) << 1)) * 16);
    const int aC2 = (4 + l5) * 512 + ((l31 ^ (((4 + l5) & 3) << 1)) * 16);
    const int aC3 = (6 + l5) * 512 + ((l31 ^ (((6 + l5) & 3) << 1)) * 16);
    const int bC0 = (0 + l5) * 512 + l31 * 16;
    const int bC1 = (2 + l5) * 512 + l31 * 16;
    const int bC2 = (4 + l5) * 512 + l31 * 16;
    const int bC3 = (6 + l5) * 512 + l31 * 16;

#define B_STAGE(br, tb) { \
    _Pragma("unroll") for (int n = 0; n < 4; ++n) \
        gload_lds16(bSrc + (tb) + n * 8192, \
                    lds + 32768 + (br) * 32768 + n * 8192 + tid16); }
#define A_LOAD_E(kpb) { \
    rAe0 = *(const bf16x8*)(aSrcK + (kpb) + aoffB); \
    rAe1 = *(const bf16x8*)(aSrcK + (kpb) + aoffB + 64); }
#define A_LOAD_O(kpb) { \
    rAo0 = *(const bf16x8*)(aSrcK + (kpb) + aoffB); \
    rAo1 = *(const bf16x8*)(aSrcK + (kpb) + aoffB + 64); }
#define A_WRITE_E(ab) { \
    bf16x8 s0_ = shuffle_sign(rAe0, jx, mk0, mk1, mk2, mk3); \
    bf16x8 s1_ = shuffle_sign(rAe1, jx, mk0, mk1, mk2, mk3); \
    *(bf16x8*)(lds + (ab) * 16384 + adst0) = s0_; \
    *(bf16x8*)(lds + (ab) * 16384 + adst0 + 2048) = s1_; }
#define A_WRITE_O(ab) { \
    bf16x8 s0_ = shuffle_sign(rAo0, jx, mk0, mk1, mk2, mk3); \
    bf16x8 s1_ = shuffle_sign(rAo1, jx, mk0, mk1, mk2, mk3); \
    *(bf16x8*)(lds + (ab) * 16384 + adst0) = s0_; \
    *(bf16x8*)(lds + (ab) * 16384 + adst0 + 2048) = s1_; }

// READ_G0: ks 0,1 ; READ_G1: ks 2,3
#define READ_G0(ab, br) { \
    aG0[0][0] = *(const bf16x8*)(lds + (ab)*16384 + aLp + 0*4096 + aC0); \
    aG0[0][1] = *(const bf16x8*)(lds + (ab)*16384 + aLp + 0*4096 + aC1); \
    aG0[1][0] = *(const bf16x8*)(lds + (ab)*16384 + aLp + 1*4096 + aC0); \
    aG0[1][1] = *(const bf16x8*)(lds + (ab)*16384 + aLp + 1*4096 + aC1); \
    bG0[0][0] = *(const bf16x8*)(lds + (br)*32768 + bLp + 0*4096 + bC0); \
    bG0[0][1] = *(const bf16x8*)(lds + (br)*32768 + bLp + 0*4096 + bC1); \
    bG0[1][0] = *(const bf16x8*)(lds + (br)*32768 + bLp + 1*4096 + bC0); \
    bG0[1][1] = *(const bf16x8*)(lds + (br)*32768 + bLp + 1*4096 + bC1); }
#define READ_G1(ab, br) { \
    aG1[0][0] = *(const bf16x8*)(lds + (ab)*16384 + aLp + 0*4096 + aC2); \
    aG1[0][1] = *(const bf16x8*)(lds + (ab)*16384 + aLp + 0*4096 + aC3); \
    aG1[1][0] = *(const bf16x8*)(lds + (ab)*16384 + aLp + 1*4096 + aC2); \
    aG1[1][1] = *(const bf16x8*)(lds + (ab)*16384 + aLp + 1*4096 + aC3); \
    bG1[0][0] = *(const bf16x8*)(lds + (br)*32768 + bLp + 0*4096 + bC2); \
    bG1[0][1] = *(const bf16x8*)(lds + (br)*32768 + bLp + 0*4096 + bC3); \
    bG1[1][0] = *(const bf16x8*)(lds + (br)*32768 + bLp + 1*4096 + bC2); \
    bG1[1][1] = *(const bf16x8*)(lds + (br)*32768 + bLp + 1*4096 + bC3); }
#define MFG0() \
    _Pragma("unroll") for (int s = 0; s < 2; ++s) \
    _Pragma("unroll") for (int mt = 0; mt < 2; ++mt) \
    _Pragma("unroll") for (int nt = 0; nt < 2; ++nt) \
        acc[mt][nt] = __builtin_amdgcn_mfma_f32_32x32x16_bf16(aG0[mt][s], bG0[nt][s], acc[mt][nt], 0, 0, 0);
#define MFG1() \
    _Pragma("unroll") for (int s = 0; s < 2; ++s) \
    _Pragma("unroll") for (int mt = 0; mt < 2; ++mt) \
    _Pragma("unroll") for (int nt = 0; nt < 2; ++nt) \
        acc[mt][nt] = __builtin_amdgcn_mfma_f32_32x32x16_bf16(aG1[mt][s], bG1[nt][s], acc[mt][nt], 0, 0, 0);

    f32x16 acc[2][2];
#pragma unroll
    for (int mt = 0; mt < 2; ++mt)
#pragma unroll
        for (int nt = 0; nt < 2; ++nt) acc[mt][nt] = (f32x16)0.0f;

    bf16x8 rAe0, rAe1, rAo0, rAo1;
    bf16x8 aG0[2][2], bG0[2][2], aG1[2][2], bG1[2][2];

    // ---- prologue: establish entry invariant {Bg(1) 4, Ar(1) 2, Bg(2) 4} = 10,
    //      A(0) written (lgkm drained), B(0) complete.
    A_LOAD_E(0);            // Ar(0)              [2]
    SCHED0();
    B_STAGE(0, 0);          // Bg(0)              [6]
    SCHED0();
    VMC(4);                 // retire Ar(0)
    A_WRITE_E(0);           // A(0) -> abuf0
    SCHED0();
    B_STAGE(1, 32768);      // Bg(1)              [8]
    SCHED0();
    A_LOAD_O(128);          // Ar(1)              [10]
    SCHED0();
    B_STAGE(2, 65536);      // Bg(2)              [14]
    SCHED0();
    VMC(10);                // retire Bg(0) -> pending {Bg1,Ar1,Bg2} = 10
    LGKM(0);                // A(0) writes visible
    BAR();

    // body: entry pending {Bg(T+1) 4, Ar(T+1) 2, Bg(T+2) 4}; VMC(4) retires the
    // first 6 (all issued >=1 tile ago). 1 barrier/tile, waits only at entry+LGKM.
#define TILE32(AB, ABN, BR, BRS, ALOAD, AWRITE, Texp) { \
    const int T_ = (Texp); \
    const int  kAr = ((T_ + 2) & 127) << 7; \
    const long kBg = (long)((T_ + 3) & 127) << 15; \
    VMC(4);                /* Bg(T+1)+Ar(T+1) retired */ \
    AWRITE(ABN); \
    SCHED0(); \
    READ_G0(AB, BR); \
    SCHED0(); \
    READ_G1(AB, BR); \
    SCHED0(); \
    ALOAD(kAr);            /* Ar(T+2), 2 vm */ \
    SCHED0(); \
    B_STAGE(BRS, kBg);     /* Bg(T+3), 4 vm */ \
    SCHED0(); \
    LGKM(8); MFG0(); \
    LGKM(0); MFG1(); \
    BAR(); }

    for (int t = 0; t < 32; ++t) {
        const int T4 = t * 4;
        TILE32(0, 1, 0, 3, A_LOAD_E, A_WRITE_O, T4);
        TILE32(1, 0, 1, 0, A_LOAD_O, A_WRITE_E, T4 + 1);
        TILE32(0, 1, 2, 1, A_LOAD_E, A_WRITE_O, T4 + 2);
        TILE32(1, 0, 3, 2, A_LOAD_O, A_WRITE_E, T4 + 3);
    }

    // ---- epilogue: 32x32 C/D layout col=lane&31, row=(r&3)+8*(r>>2)+4*l5 (m74/m101)
#pragma unroll
    for (int mt = 0; mt < 2; ++mt)
#pragma unroll
        for (int nt = 0; nt < 2; ++nt) {
            long c = (long)kblk * 256 + wc * 64 + nt * 32 + l31;
#pragma unroll
            for (int r = 0; r < 16; ++r) {
                int  rl = (r & 3) + 8 * (r >> 2) + 4 * l5;
                long rb = row0 + wr * 64 + mt * 32 + rl;
                Cws[rb * N_DIM + c] = acc[mt][nt][r];
            }
        }

#undef B_STAGE
#undef A_LOAD_E
#undef A_LOAD_O
#undef A_WRITE_E
#undef A_WRITE_O
#undef READ_G0
#undef READ_G1
#undef MFG0
#undef MFG1
#undef TILE32
}

// ---------- transpose: out[b][o*32+k] = Cws[b][k*256+o] ----------
__global__ __launch_bounds__(256) void transpose_kernel(const float* __restrict__ Cws,
                                                        float* __restrict__ out) {
    __shared__ float t[32 * 260];
    const int tid = threadIdx.x;
    const long b  = blockIdx.x;
    const float4* src = (const float4*)(Cws + b * N_DIM);
    float4*       dst = (float4*)(out + b * N_DIM);
#pragma unroll
    for (int r = 0; r < 8; ++r) {
        int f = tid + r * 256;
        float4 v = src[f];
        int k  = f >> 6;
        int c4 = (f & 63) * 4;
        *(float4*)&t[k * 260 + c4] = v;
    }
    __syncthreads();
#pragma unroll
    for (int r = 0; r < 8; ++r) {
        int g  = tid + r * 256;
        int o  = g >> 3;
        int k0 = (g & 7) * 4;
        float4 v;
        v.x = t[(k0 + 0) * 260 + o];
        v.y = t[(k0 + 1) * 260 + o];
        v.z = t[(k0 + 2) * 260 + o];
        v.w = t[(k0 + 3) * 260 + o];
        dst[g] = v;
    }
}

// ---------- fallback (ws tiny): direct fp32, correct but slow ----------
__global__ __launch_bounds__(256) void fallback_gp_kernel(const float* __restrict__ x,
                                                          const float* __restrict__ w,
                                                          float* __restrict__ out) {
    __shared__ float xs[IN_DIM * 32];
    __shared__ float tab[1024];
    int tid = threadIdx.x;
    for (int idx = tid; idx < 1024; idx += 256) {
        int m = idx >> 5, k = idx & 31;
        tab[idx] = gp_sign(m, m ^ k);
    }
    int b = blockIdx.x;
    const float4* xrow = (const float4*)(x + (long)b * K_DIM);
    float4* xs4 = (float4*)xs;
    for (int idx = tid; idx < 2048; idx += 256) xs4[idx] = xrow[idx];
    __syncthreads();

    int wid = tid >> 6, lane = tid & 63;
    int o = blockIdx.y * 8 + wid;
    int k = lane & 31, half = lane >> 5;
    float acc = 0.f;
    const float* wrow = w + (long)o * K_DIM + half * 4096;
    for (int i = 0; i < 128; ++i) {
        int ib = (half * 128 + i) * 32;
#pragma unroll
        for (int m = 0; m < 32; ++m) {
            acc += xs[ib + (m ^ k)] * tab[m * 32 + k] * wrow[i * 32 + m];
        }
    }
    acc += __shfl_down(acc, 32);
    if (half == 0) out[((long)b * OUT_DIM + o) * 32 + k] = acc;
}

// ---------- launch ----------
extern "C" void kernel_launch(void* const* d_in, const int* in_sizes, int n_in,
                              void* d_out, int out_size, void* d_ws, size_t ws_size,
                              hipStream_t stream) {
    const float* x = (const float*)d_in[0];
    const float* w = (const float*)d_in[1];
    float* out = (float*)d_out;

    const size_t xb_bytes  = (size_t)B_DIM * K_DIM * 2;          // 16 MiB
    const size_t wb_bytes  = (size_t)OUT_DIM * IN_DIM * 32 * 2;  // 4.2 MB
    const size_t cw_bytes  = (size_t)B_DIM * N_DIM * 4;          // 32 MiB
    const size_t need = xb_bytes + wb_bytes + cw_bytes;          // ~54 MB

    if (ws_size >= need) {
        unsigned short* xbp = (unsigned short*)d_ws;
        unsigned short* wbp = (unsigned short*)((char*)d_ws + xb_bytes);
        float*          cws = (float*)((char*)d_ws + xb_bytes + wb_bytes);

        cast_kernel<<<dim3(4096), dim3(256), 0, stream>>>((const float4*)x, xbp);
        cast_w_perm_kernel<<<dim3(1024), dim3(256), 0, stream>>>(w, wbp);
        gemm_ko32_kernel<<<dim3(32, 8), dim3(512), 0, stream>>>(xbp, wbp, cws);
        transpose_kernel<<<dim3(B_DIM), dim3(256), 0, stream>>>(cws, out);
    } else {
        fallback_gp_kernel<<<dim3(B_DIM, OUT_DIM / 8), dim3(256), 0, stream>>>(x, w, out);
    }
}